// Round 2
// baseline (1392.324 us; speedup 1.0000x reference)
//
#include <hip/hip_runtime.h>
#include <hip/hip_fp16.h>

// ---------------------------------------------------------------------------
// MLPForwardPolicy: x = relu(relu(relu(s@W1+b1)@W2+b2)@W3+b3)
//   action = softmax(x[:,:8960]@Wa+ba); p1 = softmax(x[:,8960:]@Ws+bs)
//   p2 = softmax(where(mask,-1e9,p1)); scores = where(mask,-inf,log p2 + g(u))
//   idx = argmax -> coords; out0 = action * p2[idx]
//
// Precision: f16x2 split GEMM (hi+lo planes both operands, 3 MFMA terms)
// -> per-product rel err ~2^-22, keeps the Gumbel argmax exact vs f32 ref.
// Memory: W (1.28 GB f32) streamed exactly once (BM=256 = whole batch).
// A-fragments read direct global->reg (L2/L3 resident); only W goes via LDS
// (split hi/lo, double-buffered, 1 barrier/step). splitK=2 -> 288 blocks.
// ---------------------------------------------------------------------------

typedef _Float16 f16;
typedef _Float16 f16x4 __attribute__((ext_vector_type(4)));
typedef _Float16 f16x8 __attribute__((ext_vector_type(8)));
typedef float f32x4 __attribute__((ext_vector_type(4)));

#define DH 9216
#define SPLIT 8960

// ---------------- f32 -> (hi,lo) f16 planes ----------------
__global__ void cvt_kernel(const float* __restrict__ in, f16* __restrict__ oh,
                           f16* __restrict__ ol, int n) {
    for (int i = (blockIdx.x * blockDim.x + threadIdx.x) * 4; i < n;
         i += gridDim.x * blockDim.x * 4) {
        float4 v = *(const float4*)(in + i);
        f16x4 h, l;
        h[0] = (_Float16)v.x; l[0] = (_Float16)(v.x - (float)h[0]);
        h[1] = (_Float16)v.y; l[1] = (_Float16)(v.y - (float)h[1]);
        h[2] = (_Float16)v.z; l[2] = (_Float16)(v.z - (float)h[2]);
        h[3] = (_Float16)v.w; l[3] = (_Float16)(v.w - (float)h[3]);
        *(f16x4*)(oh + i) = h;
        *(f16x4*)(ol + i) = l;
    }
}

// ---------------- split-f16 streaming GEMM ----------------
// P[ky] = A[256, K] @ W[K, 9216], grid (144, 2), block 256 (4 waves)
// wave w owns rows [w*64, w*64+64) x cols [n0, n0+64)
__global__ __launch_bounds__(256, 2) void gemm_kernel(
    const f16* __restrict__ Ah, const f16* __restrict__ Al, int K,
    const float* __restrict__ W,
    float* __restrict__ P)   // [2][256][9216]
{
    __shared__ __align__(16) f16 Wt[2][2][64][40];  // [buf][plane][n][k(32)+8 pad]
    const int tid  = threadIdx.x;
    const int lane = tid & 63;
    const int wid  = tid >> 6;
    const int n0   = blockIdx.x * 64;
    const int kbase = blockIdx.y * (K >> 1);
    const int nsteps = K >> 6;          // (K/2)/32, even (256 or 144)
    const int kq = tid >> 6, cc = tid & 63;

    f32x4 acc[4][4] = {};
    float wcur[8], wnxt[8];
    f16x8 aH[4], aL[4], aHn[4], aLn[4];

    auto loadW = [&](float* dst, int t) {
        const size_t base = (size_t)(kbase + (t << 5) + kq * 8) * DH + n0 + cc;
#pragma unroll
        for (int j = 0; j < 8; ++j) dst[j] = W[base + (size_t)j * DH];
    };
    auto loadA = [&](f16x8* h, f16x8* l, int t) {
        const int k0 = kbase + (t << 5) + ((lane >> 4) << 3);
#pragma unroll
        for (int ri = 0; ri < 4; ++ri) {
            const size_t off = (size_t)(wid * 64 + ri * 16 + (lane & 15)) * K + k0;
            h[ri] = *(const f16x8*)(Ah + off);
            l[ri] = *(const f16x8*)(Al + off);
        }
    };
    auto writeW = [&](const float* src, int buf) {
        f16x8 hi, lo;
#pragma unroll
        for (int j = 0; j < 8; ++j) {
            _Float16 h = (_Float16)src[j];
            hi[j] = h;
            lo[j] = (_Float16)(src[j] - (float)h);
        }
        *(f16x8*)&Wt[buf][0][cc][kq * 8] = hi;
        *(f16x8*)&Wt[buf][1][cc][kq * 8] = lo;
    };

    loadW(wcur, 0);
    loadA(aH, aL, 0);
    writeW(wcur, 0);
    __syncthreads();

    for (int t = 0; t < nsteps; t += 2) {
        // ---- phase A: compute step t from buf 0 ----
        loadW(wnxt, t + 1);                      // t+1 <= nsteps-1, valid
        loadA(aHn, aLn, t + 1);
#pragma unroll
        for (int ni = 0; ni < 4; ++ni) {
            f16x8 bh = *(const f16x8*)&Wt[0][0][ni * 16 + (lane & 15)][(lane >> 4) * 8];
            f16x8 bl = *(const f16x8*)&Wt[0][1][ni * 16 + (lane & 15)][(lane >> 4) * 8];
#pragma unroll
            for (int ri = 0; ri < 4; ++ri) {
                acc[ri][ni] = __builtin_amdgcn_mfma_f32_16x16x32_f16(aH[ri], bh, acc[ri][ni], 0, 0, 0);
                acc[ri][ni] = __builtin_amdgcn_mfma_f32_16x16x32_f16(aH[ri], bl, acc[ri][ni], 0, 0, 0);
                acc[ri][ni] = __builtin_amdgcn_mfma_f32_16x16x32_f16(aL[ri], bh, acc[ri][ni], 0, 0, 0);
            }
        }
        writeW(wnxt, 1);
        __syncthreads();

        // ---- phase B: compute step t+1 from buf 1 ----
        const int t2 = (t + 2 < nsteps) ? t + 2 : 0;   // last prefetch unused
        loadW(wcur, t2);
        loadA(aH, aL, t2);
#pragma unroll
        for (int ni = 0; ni < 4; ++ni) {
            f16x8 bh = *(const f16x8*)&Wt[1][0][ni * 16 + (lane & 15)][(lane >> 4) * 8];
            f16x8 bl = *(const f16x8*)&Wt[1][1][ni * 16 + (lane & 15)][(lane >> 4) * 8];
#pragma unroll
            for (int ri = 0; ri < 4; ++ri) {
                acc[ri][ni] = __builtin_amdgcn_mfma_f32_16x16x32_f16(aHn[ri], bh, acc[ri][ni], 0, 0, 0);
                acc[ri][ni] = __builtin_amdgcn_mfma_f32_16x16x32_f16(aHn[ri], bl, acc[ri][ni], 0, 0, 0);
                acc[ri][ni] = __builtin_amdgcn_mfma_f32_16x16x32_f16(aLn[ri], bh, acc[ri][ni], 0, 0, 0);
            }
        }
        writeW(wcur, 0);
        __syncthreads();
    }

    // epilogue: D layout col=lane&15, row=(lane>>4)*4+reg  [m89-verified]
    float* Pb = P + (size_t)blockIdx.y * (256 * DH);
#pragma unroll
    for (int ri = 0; ri < 4; ++ri) {
        int row = wid * 64 + ri * 16 + ((lane >> 4) << 2);
#pragma unroll
        for (int ni = 0; ni < 4; ++ni) {
            int col = n0 + ni * 16 + (lane & 15);
#pragma unroll
            for (int rg = 0; rg < 4; ++rg)
                Pb[(size_t)(row + rg) * DH + col] = acc[ri][ni][rg];
        }
    }
}

// ---------------- splitK reduce + bias + relu -> hi/lo planes or f32 -------
__global__ void reduce_kernel(const float* __restrict__ P,
                              const float* __restrict__ bias,
                              f16* __restrict__ oh, f16* __restrict__ ol,
                              float* __restrict__ out32) {
    const int n = 256 * DH;
    for (int i = (blockIdx.x * blockDim.x + threadIdx.x) * 4; i < n;
         i += gridDim.x * blockDim.x * 4) {
        float4 a = *(const float4*)(P + i);
        float4 b = *(const float4*)(P + n + i);
        float4 bb = *(const float4*)(bias + (i % DH));
        float4 r;
        r.x = fmaxf(a.x + b.x + bb.x, 0.f);
        r.y = fmaxf(a.y + b.y + bb.y, 0.f);
        r.z = fmaxf(a.z + b.z + bb.z, 0.f);
        r.w = fmaxf(a.w + b.w + bb.w, 0.f);
        if (oh) {
            f16x4 h, l;
            h[0] = (_Float16)r.x; l[0] = (_Float16)(r.x - (float)h[0]);
            h[1] = (_Float16)r.y; l[1] = (_Float16)(r.y - (float)h[1]);
            h[2] = (_Float16)r.z; l[2] = (_Float16)(r.z - (float)h[2]);
            h[3] = (_Float16)r.w; l[3] = (_Float16)(r.w - (float)h[3]);
            *(f16x4*)(oh + i) = h;
            *(f16x4*)(ol + i) = l;
        }
        if (out32) *(float4*)(out32 + i) = r;
    }
}

// ---------------- action head: softmax(X3[:, :8960] @ Wa + ba) --------------
__global__ __launch_bounds__(256) void action_kernel(
    const float* __restrict__ X3, const float* __restrict__ Wa,
    const float* __restrict__ ba, float* __restrict__ xact) {
    __shared__ float xs[SPLIT];
    __shared__ float red[256];
    const int row = blockIdx.x, t = threadIdx.x;
    const float* xr = X3 + (size_t)row * DH;
    for (int k = t * 4; k < SPLIT; k += 1024)
        *(float4*)&xs[k] = *(const float4*)(xr + k);
    __syncthreads();
    const int col = t & 63, kqq = t >> 6;
    float acc = 0.f;
    for (int k = kqq * 2240; k < (kqq + 1) * 2240; ++k)
        acc += xs[k] * Wa[(size_t)k * 64 + col];
    red[t] = acc;
    __syncthreads();
    if (t < 64) {
        float z = red[t] + red[t + 64] + red[t + 128] + red[t + 192] + ba[t];
        float mx = z;
        for (int off = 32; off; off >>= 1) mx = fmaxf(mx, __shfl_xor(mx, off));
        float e = expf(z - mx);
        float s = e;
        for (int off = 32; off; off >>= 1) s += __shfl_xor(s, off);
        xact[row * 64 + t] = e / s;
    }
}

// ---------------- selection head + final outputs ---------------------------
__global__ __launch_bounds__(256) void select_kernel(
    const float* __restrict__ X3, const float* __restrict__ Ws,
    const float* __restrict__ bs, const void* __restrict__ maskp,
    const float* __restrict__ u, const float* __restrict__ xact,
    float* __restrict__ out) {
    __shared__ float xs[256];
    __shared__ float psh[256];
    __shared__ float rr[4];
    __shared__ float bestv[4];
    __shared__ int besti[4];
    __shared__ int sIdx;
    __shared__ int smode;
    const int row = blockIdx.x, t = threadIdx.x;
    const int lane = t & 63, wid = t >> 6;

    // mask dtype detection: int32 {0,1} / bytes {0,1} / float {0.f,1.f}
    if (t < 64) {
        unsigned v = ((const unsigned*)maskp)[t];
        int okInt  = __all(v <= 1u);
        int okByte = __all((v & 0xFEFEFEFEu) == 0u);
        if (t == 0) smode = okInt ? 0 : (okByte ? 1 : 2);
    }
    xs[t] = X3[(size_t)row * DH + SPLIT + t];
    __syncthreads();

    bool mk;
    if (smode == 0)       mk = ((const int*)maskp)[row * 256 + t] != 0;
    else if (smode == 1)  mk = ((const unsigned char*)maskp)[row * 256 + t] != 0;
    else                  mk = ((const float*)maskp)[row * 256 + t] != 0.0f;

    float z = bs[t];
    for (int k = 0; k < 256; ++k)
        z += xs[k] * Ws[k * 256 + t];

    // softmax #1
    float v = z;
    for (int off = 32; off; off >>= 1) v = fmaxf(v, __shfl_xor(v, off));
    if (lane == 0) rr[wid] = v;
    __syncthreads();
    float m1 = fmaxf(fmaxf(rr[0], rr[1]), fmaxf(rr[2], rr[3]));
    __syncthreads();
    float e1 = expf(z - m1);
    v = e1;
    for (int off = 32; off; off >>= 1) v += __shfl_xor(v, off);
    if (lane == 0) rr[wid] = v;
    __syncthreads();
    float s1 = rr[0] + rr[1] + rr[2] + rr[3];
    __syncthreads();
    float p1 = e1 / s1;

    // mask, softmax #2
    float q = mk ? -1e9f : p1;
    v = q;
    for (int off = 32; off; off >>= 1) v = fmaxf(v, __shfl_xor(v, off));
    if (lane == 0) rr[wid] = v;
    __syncthreads();
    float m2 = fmaxf(fmaxf(rr[0], rr[1]), fmaxf(rr[2], rr[3]));
    __syncthreads();
    float e2 = expf(q - m2);
    v = e2;
    for (int off = 32; off; off >>= 1) v += __shfl_xor(v, off);
    if (lane == 0) rr[wid] = v;
    __syncthreads();
    float s2 = rr[0] + rr[1] + rr[2] + rr[3];
    float p2 = e2 / s2;
    psh[t] = p2;

    // gumbel scores + first-occurrence argmax
    float g = -logf(-logf(u[row * 256 + t]));
    float sc = mk ? -INFINITY : (logf(p2) + g);
    float bv = sc;
    int bi = t;
    for (int off = 32; off; off >>= 1) {
        float ov = __shfl_xor(bv, off);
        int oi = __shfl_xor(bi, off);
        if (ov > bv || (ov == bv && oi < bi)) { bv = ov; bi = oi; }
    }
    if (lane == 0) { bestv[wid] = bv; besti[wid] = bi; }
    __syncthreads();
    if (t == 0) {
        float fv = bestv[0];
        int fi = besti[0];
        for (int w = 1; w < 4; ++w)
            if (bestv[w] > fv || (bestv[w] == fv && besti[w] < fi)) {
                fv = bestv[w]; fi = besti[w];
            }
        sIdx = fi;
    }
    __syncthreads();
    const int idx = sIdx;
    const float sp = psh[idx];
    if (t < 64) out[row * 64 + t] = xact[row * 64 + t] * sp;
    if (t == 0) {
        out[256 * 64 + row * 2 + 0] = (float)(idx >> 4);
        out[256 * 64 + row * 2 + 1] = (float)(idx & 15);
    }
}

// ---------------------------------------------------------------------------
extern "C" void kernel_launch(void* const* d_in, const int* in_sizes, int n_in,
                              void* d_out, int out_size, void* d_ws, size_t ws_size,
                              hipStream_t stream) {
    const float* s  = (const float*)d_in[0];
    const void*  mask = d_in[1];              // dtype detected on device
    const float* u  = (const float*)d_in[2];
    const float* W1 = (const float*)d_in[3];
    const float* b1 = (const float*)d_in[4];
    const float* W2 = (const float*)d_in[5];
    const float* b2 = (const float*)d_in[6];
    const float* W3 = (const float*)d_in[7];
    const float* b3 = (const float*)d_in[8];
    const float* Wa = (const float*)d_in[9];
    const float* ba = (const float*)d_in[10];
    const float* Ws = (const float*)d_in[11];
    const float* bs = (const float*)d_in[12];
    float* out = (float*)d_out;
    char* ws = (char*)d_ws;

    // workspace map (45.2 MB, regions reused once dead):
    f16*   A0h = (f16*)(ws + 0);            // 8,388,608   [256][16384]
    f16*   A0l = (f16*)(ws + 8388608);      // 8,388,608
    f16*   X1h = (f16*)(ws + 16777216);     // 4,718,592   [256][9216]
    f16*   X1l = (f16*)(ws + 21495808);     // 4,718,592
    f16*   X2h = (f16*)(ws + 0);            // reuses dead A0h
    f16*   X2l = (f16*)(ws + 4718592);      // reuses dead A0h/A0l
    float* X3  = (float*)(ws + 9437184);    // 9,437,184, reuses dead A0/X1h head
    float* P   = (float*)(ws + 26214400);   // 18,874,368  [2][256][9216]
    float* XA  = (float*)(ws + 45088768);   //    65,536

    cvt_kernel<<<2048, 256, 0, stream>>>(s, A0h, A0l, 256 * 16384);

    dim3 ggrid(144, 2);
    gemm_kernel<<<ggrid, 256, 0, stream>>>(A0h, A0l, 16384, W1, P);
    reduce_kernel<<<1152, 256, 0, stream>>>(P, b1, X1h, X1l, nullptr);
    gemm_kernel<<<ggrid, 256, 0, stream>>>(X1h, X1l, DH, W2, P);
    reduce_kernel<<<1152, 256, 0, stream>>>(P, b2, X2h, X2l, nullptr);
    gemm_kernel<<<ggrid, 256, 0, stream>>>(X2h, X2l, DH, W3, P);
    reduce_kernel<<<1152, 256, 0, stream>>>(P, b3, nullptr, nullptr, X3);

    action_kernel<<<256, 256, 0, stream>>>(X3, Wa, ba, XA);
    select_kernel<<<256, 256, 0, stream>>>(X3, Ws, bs, mask, u, XA, out);
}

// Round 3
// 663.535 us; speedup vs baseline: 2.0983x; 2.0983x over previous
//
#include <hip/hip_runtime.h>
#include <hip/hip_fp16.h>

// ---------------------------------------------------------------------------
// MLPForwardPolicy — plain-f16 MFMA streaming GEMMs (memory-bound design).
// Error budget: f16 GEMM gives dz ~1e-4; double-softmax damps selection-score
// error to ~4e-7 (flip prob ~1e-4/call); out0 abs err ~1e-4 << 0.3 threshold.
// Occupancy fix vs round 2: splitK=8 -> 1152 blocks, 3 blocks/CU resident.
// ---------------------------------------------------------------------------

typedef _Float16 f16;
typedef _Float16 f16x4 __attribute__((ext_vector_type(4)));
typedef _Float16 f16x8 __attribute__((ext_vector_type(8)));
typedef float f32x4 __attribute__((ext_vector_type(4)));

#define DH 9216
#define SPLIT 8960

// ---------------- f32 -> f16 ----------------
__global__ void cvt_kernel(const float* __restrict__ in, f16* __restrict__ out, int n) {
    for (int i = (blockIdx.x * blockDim.x + threadIdx.x) * 4; i < n;
         i += gridDim.x * blockDim.x * 4) {
        float4 v = *(const float4*)(in + i);
        f16x4 h = {(_Float16)v.x, (_Float16)v.y, (_Float16)v.z, (_Float16)v.w};
        *(f16x4*)(out + i) = h;
    }
}

// ---------------- streaming GEMM: P[ky] = A[256,Kh] @ W[Kh,9216] ------------
// grid (144, S); block 256 (4 waves; wave w owns rows w*64..+64 x cols n0..+64)
__global__ __launch_bounds__(256, 3) void gemm_kernel(
    const f16* __restrict__ A, int K, int Kh,
    const float* __restrict__ W,
    float* __restrict__ P)   // [S][256][9216]
{
    __shared__ __align__(16) f16 Wt[2][64][40];   // [buf][n][k(32)+8 pad]
    const int tid  = threadIdx.x;
    const int lane = tid & 63;
    const int wid  = tid >> 6;
    const int n0   = blockIdx.x * 64;
    const int kbase = blockIdx.y * Kh;
    const int nsteps = Kh >> 5;                   // even for all S in {2,4,8}
    const int cc = tid & 63, kq = tid >> 6;

    f32x4 acc[4][4] = {};
    float wA[8], wB[8];
    f16x8 aA[4], aB[4];

    auto loadW = [&](float* dst, int t) {
        const size_t base = (size_t)(kbase + (t << 5) + kq * 8) * DH + n0 + cc;
#pragma unroll
        for (int j = 0; j < 8; ++j) dst[j] = W[base + (size_t)j * DH];
    };
    auto loadA = [&](f16x8* a, int t) {
        const int k0 = kbase + (t << 5) + ((lane >> 4) << 3);
#pragma unroll
        for (int ri = 0; ri < 4; ++ri)
            a[ri] = *(const f16x8*)(A + (size_t)(wid * 64 + ri * 16 + (lane & 15)) * K + k0);
    };
    auto writeW = [&](const float* src, int buf) {
        f16x8 h;
#pragma unroll
        for (int j = 0; j < 8; ++j) h[j] = (_Float16)src[j];
        *(f16x8*)&Wt[buf][cc][kq * 8] = h;
    };
    auto mfma_step = [&](int buf, f16x8* a) {
        f16x8 bf[4];
#pragma unroll
        for (int ni = 0; ni < 4; ++ni)
            bf[ni] = *(const f16x8*)&Wt[buf][ni * 16 + (lane & 15)][(lane >> 4) * 8];
#pragma unroll
        for (int ri = 0; ri < 4; ++ri)
#pragma unroll
            for (int ni = 0; ni < 4; ++ni)
                acc[ri][ni] = __builtin_amdgcn_mfma_f32_16x16x32_f16(
                    a[ri], bf[ni], acc[ri][ni], 0, 0, 0);
    };

    loadW(wA, 0); loadA(aA, 0);
    writeW(wA, 0);
    loadW(wB, 1); loadA(aB, 1);
    __syncthreads();

    for (int t = 0; t < nsteps; t += 2) {
        // phase A: compute step t from buf0; stage W(t+1)->buf1; prefetch t+2
        writeW(wB, 1);
        if (t + 2 < nsteps) loadW(wA, t + 2);
        mfma_step(0, aA);
        if (t + 2 < nsteps) loadA(aA, t + 2);
        __syncthreads();
        // phase B: compute step t+1 from buf1; stage W(t+2)->buf0; prefetch t+3
        if (t + 2 < nsteps) writeW(wA, 0);
        if (t + 3 < nsteps) loadW(wB, t + 3);
        mfma_step(1, aB);
        if (t + 3 < nsteps) loadA(aB, t + 3);
        __syncthreads();
    }

    // epilogue: D layout col=lane&15, row=(lane>>4)*4+reg  [m89-verified]
    float* Pb = P + (size_t)blockIdx.y * (256 * DH);
#pragma unroll
    for (int ri = 0; ri < 4; ++ri) {
        int row = wid * 64 + ri * 16 + ((lane >> 4) << 2);
#pragma unroll
        for (int ni = 0; ni < 4; ++ni) {
            int col = n0 + ni * 16 + (lane & 15);
#pragma unroll
            for (int rg = 0; rg < 4; ++rg)
                Pb[(size_t)(row + rg) * DH + col] = acc[ri][ni][rg];
        }
    }
}

// ---------------- splitK reduce + bias + relu -> f16 and/or f32 -------------
__global__ void reduce_kernel(const float* __restrict__ P, int S,
                              const float* __restrict__ bias,
                              f16* __restrict__ oh, float* __restrict__ out32) {
    const int n = 256 * DH;
    for (int i = (blockIdx.x * blockDim.x + threadIdx.x) * 4; i < n;
         i += gridDim.x * blockDim.x * 4) {
        float4 bb = *(const float4*)(bias + (i % DH));
        float4 r = bb;
        for (int j = 0; j < S; ++j) {
            float4 a = *(const float4*)(P + (size_t)j * n + i);
            r.x += a.x; r.y += a.y; r.z += a.z; r.w += a.w;
        }
        r.x = fmaxf(r.x, 0.f); r.y = fmaxf(r.y, 0.f);
        r.z = fmaxf(r.z, 0.f); r.w = fmaxf(r.w, 0.f);
        if (oh) {
            f16x4 h = {(_Float16)r.x, (_Float16)r.y, (_Float16)r.z, (_Float16)r.w};
            *(f16x4*)(oh + i) = h;
        }
        if (out32) *(float4*)(out32 + i) = r;
    }
}

// ---------------- action head: softmax(X3[:, :8960] @ Wa + ba) --------------
__global__ __launch_bounds__(256) void action_kernel(
    const float* __restrict__ X3, const float* __restrict__ Wa,
    const float* __restrict__ ba, float* __restrict__ xact) {
    __shared__ float xs[SPLIT];
    __shared__ float red[256];
    const int row = blockIdx.x, t = threadIdx.x;
    const float* xr = X3 + (size_t)row * DH;
    for (int k = t * 4; k < SPLIT; k += 1024)
        *(float4*)&xs[k] = *(const float4*)(xr + k);
    __syncthreads();
    const int col = t & 63, kqq = t >> 6;
    float acc = 0.f;
    for (int k = kqq * 2240; k < (kqq + 1) * 2240; ++k)
        acc += xs[k] * Wa[(size_t)k * 64 + col];
    red[t] = acc;
    __syncthreads();
    if (t < 64) {
        float z = red[t] + red[t + 64] + red[t + 128] + red[t + 192] + ba[t];
        float mx = z;
        for (int off = 32; off; off >>= 1) mx = fmaxf(mx, __shfl_xor(mx, off));
        float e = expf(z - mx);
        float s = e;
        for (int off = 32; off; off >>= 1) s += __shfl_xor(s, off);
        xact[row * 64 + t] = e / s;
    }
}

// ---------------- selection head + final outputs ---------------------------
__global__ __launch_bounds__(256) void select_kernel(
    const float* __restrict__ X3, const float* __restrict__ Ws,
    const float* __restrict__ bs, const void* __restrict__ maskp,
    const float* __restrict__ u, const float* __restrict__ xact,
    float* __restrict__ out) {
    __shared__ float xs[256];
    __shared__ float psh[256];
    __shared__ float rr[4];
    __shared__ float bestv[4];
    __shared__ int besti[4];
    __shared__ int sIdx;
    __shared__ int smode;
    const int row = blockIdx.x, t = threadIdx.x;
    const int lane = t & 63, wid = t >> 6;

    // mask dtype detection: int32 {0,1} / bytes {0,1} / float {0.f,1.f}
    if (t < 64) {
        unsigned v = ((const unsigned*)maskp)[t];
        int okInt  = __all(v <= 1u);
        int okByte = __all((v & 0xFEFEFEFEu) == 0u);
        if (t == 0) smode = okInt ? 0 : (okByte ? 1 : 2);
    }
    xs[t] = X3[(size_t)row * DH + SPLIT + t];
    __syncthreads();

    bool mk;
    if (smode == 0)       mk = ((const int*)maskp)[row * 256 + t] != 0;
    else if (smode == 1)  mk = ((const unsigned char*)maskp)[row * 256 + t] != 0;
    else                  mk = ((const float*)maskp)[row * 256 + t] != 0.0f;

    float z = bs[t];
    for (int k = 0; k < 256; ++k)
        z += xs[k] * Ws[k * 256 + t];

    // softmax #1
    float v = z;
    for (int off = 32; off; off >>= 1) v = fmaxf(v, __shfl_xor(v, off));
    if (lane == 0) rr[wid] = v;
    __syncthreads();
    float m1 = fmaxf(fmaxf(rr[0], rr[1]), fmaxf(rr[2], rr[3]));
    __syncthreads();
    float e1 = expf(z - m1);
    v = e1;
    for (int off = 32; off; off >>= 1) v += __shfl_xor(v, off);
    if (lane == 0) rr[wid] = v;
    __syncthreads();
    float s1 = rr[0] + rr[1] + rr[2] + rr[3];
    __syncthreads();
    float p1 = e1 / s1;

    // mask, softmax #2
    float q = mk ? -1e9f : p1;
    v = q;
    for (int off = 32; off; off >>= 1) v = fmaxf(v, __shfl_xor(v, off));
    if (lane == 0) rr[wid] = v;
    __syncthreads();
    float m2 = fmaxf(fmaxf(rr[0], rr[1]), fmaxf(rr[2], rr[3]));
    __syncthreads();
    float e2 = expf(q - m2);
    v = e2;
    for (int off = 32; off; off >>= 1) v += __shfl_xor(v, off);
    if (lane == 0) rr[wid] = v;
    __syncthreads();
    float s2 = rr[0] + rr[1] + rr[2] + rr[3];
    float p2 = e2 / s2;
    psh[t] = p2;

    // gumbel scores + first-occurrence argmax
    float g = -logf(-logf(u[row * 256 + t]));
    float sc = mk ? -INFINITY : (logf(p2) + g);
    float bv = sc;
    int bi = t;
    for (int off = 32; off; off >>= 1) {
        float ov = __shfl_xor(bv, off);
        int oi = __shfl_xor(bi, off);
        if (ov > bv || (ov == bv && oi < bi)) { bv = ov; bi = oi; }
    }
    if (lane == 0) { bestv[wid] = bv; besti[wid] = bi; }
    __syncthreads();
    if (t == 0) {
        float fv = bestv[0];
        int fi = besti[0];
        for (int w = 1; w < 4; ++w)
            if (bestv[w] > fv || (bestv[w] == fv && besti[w] < fi)) {
                fv = bestv[w]; fi = besti[w];
            }
        sIdx = fi;
    }
    __syncthreads();
    const int idx = sIdx;
    const float sp = psh[idx];
    if (t < 64) out[row * 64 + t] = xact[row * 64 + t] * sp;
    if (t == 0) {
        out[256 * 64 + row * 2 + 0] = (float)(idx >> 4);
        out[256 * 64 + row * 2 + 1] = (float)(idx & 15);
    }
}

// ---------------------------------------------------------------------------
extern "C" void kernel_launch(void* const* d_in, const int* in_sizes, int n_in,
                              void* d_out, int out_size, void* d_ws, size_t ws_size,
                              hipStream_t stream) {
    const float* s  = (const float*)d_in[0];
    const void*  mask = d_in[1];
    const float* u  = (const float*)d_in[2];
    const float* W1 = (const float*)d_in[3];
    const float* b1 = (const float*)d_in[4];
    const float* W2 = (const float*)d_in[5];
    const float* b2 = (const float*)d_in[6];
    const float* W3 = (const float*)d_in[7];
    const float* b3 = (const float*)d_in[8];
    const float* Wa = (const float*)d_in[9];
    const float* ba = (const float*)d_in[10];
    const float* Ws = (const float*)d_in[11];
    const float* bs = (const float*)d_in[12];
    float* out = (float*)d_out;
    char* ws = (char*)d_ws;

    // workspace map:
    //   [0,        8,388,608)  A0 f16 [256][16384]   (reused by X2 after gemm1)
    //   [8388608, 13,107,200)  X1 f16 [256][9216]
    //   [13107200,22,544,384)  X3 f32 [256][9216]
    //   [22544384,22,609,920)  XA f32 [256][64]
    //   [22609920, ...)        P  f32 [S][256][9216]
    f16*   A0 = (f16*)(ws + 0);
    f16*   X1 = (f16*)(ws + 8388608);
    f16*   X2 = (f16*)(ws + 0);            // reuses dead A0
    float* X3 = (float*)(ws + 13107200);
    float* XA = (float*)(ws + 22544384);
    float* P  = (float*)(ws + 22609920);

    const size_t pbytes = 9437184ull;      // one splitK plane
    int S = 2;
    if (ws_size >= 22609920ull + 8 * pbytes)      S = 8;
    else if (ws_size >= 22609920ull + 4 * pbytes) S = 4;

    cvt_kernel<<<2048, 256, 0, stream>>>(s, A0, 256 * 16384);

    dim3 ggrid(144, S);
    gemm_kernel<<<ggrid, 256, 0, stream>>>(A0, 16384, 16384 / S, W1, P);
    reduce_kernel<<<1152, 256, 0, stream>>>(P, S, b1, X1, nullptr);
    gemm_kernel<<<ggrid, 256, 0, stream>>>(X1, DH, DH / S, W2, P);
    reduce_kernel<<<1152, 256, 0, stream>>>(P, S, b2, X2, nullptr);
    gemm_kernel<<<ggrid, 256, 0, stream>>>(X2, DH, DH / S, W3, P);
    reduce_kernel<<<1152, 256, 0, stream>>>(P, S, b3, nullptr, X3);

    action_kernel<<<256, 256, 0, stream>>>(X3, Wa, ba, XA);
    select_kernel<<<256, 256, 0, stream>>>(X3, Ws, bs, mask, u, XA, out);
}